// Round 16
// baseline (149.019 us; speedup 1.0000x reference)
//
#include <hip/hip_runtime.h>
#include <stdint.h>

// FSUMGUCell: hy = (1-fg)*ng + fg*hx
//   fg = ( [hx|x]@w_f^T + b_f + 1 ) * 0.5
//   ng =   [fg*hx|x]@w_n^T + b_n
// B=H=I=2048, K=H+I=4096. bf16 MFMA path.
//
// Round 16: in-block split-K at 128x64 tiles, BK=32, 3-buf LDS.
// Block = 4 waves = 2 K-groups x 2 waves; each wave owns 64x64 (4x4 acc,
// 1:2 ds_read:MFMA — r9's proven ratio); grid 512 -> 2 blocks/CU (r9's
// proven occupancy); in-LDS group reduce + fused epilogue (r3/r7-verified,
// zero cross-block traffic). LDS = 2 grp x 3 buf x 12 KB = 72 KB.
// 64B rows + XOR(row&3) chunk swizzle -> uniform 2-way bank conflict (free
// per m136). 6 loads/thread -> r14's counted vmcnt(6), 1 barrier/step.

#define Hdim 2048
#define Idim 2048
#define Bdim 2048
#define Ktot 4096
#define KHALF 2048
#define NSTEP 64            // KHALF / 32 steps per group

typedef __bf16 bf16;
typedef __bf16 bf16x8 __attribute__((ext_vector_type(8)));
typedef float  f32x4  __attribute__((ext_vector_type(4)));

__device__ __forceinline__ void gload_lds16(const bf16* g, bf16* l) {
  __builtin_amdgcn_global_load_lds(
      (const __attribute__((address_space(1))) unsigned int*)g,
      (__attribute__((address_space(3))) unsigned int*)l,
      16, 0, 0);
}

__device__ __forceinline__ void cvt8(const float* __restrict__ src, bf16* __restrict__ dst) {
  const float4* s = (const float4*)src;
  float4 a = s[0], b = s[1];
  bf16x8 o;
  o[0]=(bf16)a.x; o[1]=(bf16)a.y; o[2]=(bf16)a.z; o[3]=(bf16)a.w;
  o[4]=(bf16)b.x; o[5]=(bf16)b.y; o[6]=(bf16)b.z; o[7]=(bf16)b.w;
  *(bf16x8*)dst = o;
}

// ---- fused prep: Wf cvt | Wn cvt | A1 = [hx|x] cvt (all f32 -> bf16 x8) ----
__global__ void prep_kernel(const float* __restrict__ w_f, const float* __restrict__ w_n,
                            const float* __restrict__ hx, const float* __restrict__ x,
                            bf16* __restrict__ Wf, bf16* __restrict__ Wn,
                            bf16* __restrict__ A1) {
  const int n8 = Hdim * Ktot / 8;
  int stride = gridDim.x * blockDim.x;
  for (int i = blockIdx.x * blockDim.x + threadIdx.x; i < 3 * n8; i += stride) {
    if (i < n8) {
      cvt8(w_f + (size_t)i * 8, Wf + (size_t)i * 8);
    } else if (i < 2 * n8) {
      int j = i - n8;
      cvt8(w_n + (size_t)j * 8, Wn + (size_t)j * 8);
    } else {
      int j = i - 2 * n8;
      int e = j * 8;
      int b = e >> 12;            // / 4096
      int k = e & (Ktot - 1);
      const float* src = (k < Hdim) ? (hx + (size_t)b * Hdim + k)
                                    : (x  + (size_t)b * Idim + (k - Hdim));
      cvt8(src, A1 + (size_t)e);
    }
  }
}

// ---- 128x64 GEMM, 2-group in-block split-K, BK=32, 3-buf, fused epilogue ----
// grid 512 = 16 tm x 32 tn. C[row][col] = sum_k A[row][k] * W[col][k].
// Group g (waves 2g,2g+1) covers K in [g*2048, g*2048+2048); wave-in-group wg
// owns rows [wg*64, wg*64+64) x all 64 cols. A source per group: (Ab0,sA0) /
// (Ab1,sA1). Per-group LDS buf = A[128][32] + B[64][32] bf16 = 12 KB;
// 4-chunk-per-row XOR swizzle: LDS[row][c] holds global chunk c ^ (row&3),
// staged via inverse-swizzled global source (global_load_lds writes
// linearly); read applies the same XOR (2-way bank aliasing = free).
template<int EPI>
__global__ __launch_bounds__(256, 2)
void gemm_kernel(const bf16* __restrict__ Ab0, int sA0,
                 const bf16* __restrict__ Ab1, int sA1,
                 const bf16* __restrict__ W,
                 const float* __restrict__ bias,
                 const float* __restrict__ hx,   // EPI0 only
                 bf16* __restrict__ OMF,         // EPI0: write (1-fg) ; EPI1: read
                 bf16* __restrict__ A2L,         // EPI0: write bf16(fg*hx) ; EPI1: read
                 float* __restrict__ OUT)        // EPI1: write hy
{
  __shared__ bf16 lds[2][3][6144];   // [group][buf][A:0..4095 | B:4096..6143] = 72 KB

  int bid  = blockIdx.x;
  int sbid = (bid & 7) * 64 + (bid >> 3);   // XCD swizzle (512%8==0, bijective)
  int tm = sbid >> 5, tn = sbid & 31;       // 16 x 32 tiles of 128x64

  int tid = threadIdx.x;
  int w = tid >> 6, lane = tid & 63;
  int g = w >> 1, wg = w & 1;
  int wrow = wg * 64;           // wave's 64x64 sub-tile rows
  int fr = lane & 15, fq = lane >> 4;
  int ch = (fq ^ (fr & 3)) * 8; // read-side chunk XOR (row&3 == fr&3)

  // staging: per group-step A 512 + B 256 chunks, 128 thr -> 6 loads/thread.
  // gtid = w_in_group*64 + lane; srow = gtid>>2 (0..31); dest pos gtid&3;
  // src chunk = (gtid&3) ^ (srow&3). A pass jj(0..3): row = jj*32+srow;
  // B pass jj(0..1): row = jj*32+srow.
  int gtid = wg * 64 + lane;
  int srow = gtid >> 2;
  int csrc = (gtid & 3) ^ (srow & 3);

  const bf16* pA;
  size_t strA;
  if (EPI == 0) {
    pA = (g == 0) ? Ab0 : Ab1;                 // both = A1, offset below
    strA = (g == 0) ? (size_t)sA0 : (size_t)sA1;
    pA += (size_t)(tm * 128 + srow) * strA + csrc * 8 + g * KHALF;
  } else if (g == 0) {
    pA = Ab0 + (size_t)(tm * 128 + srow) * sA0 + csrc * 8;        // A2L (fg*hx)
    strA = sA0;
  } else {
    pA = Ab1 + (size_t)(tm * 128 + srow) * sA1 + csrc * 8;        // A1+Hdim (x)
    strA = sA1;
  }
  const bf16* pB = W + (size_t)(tn * 64 + srow) * Ktot + csrc * 8 + g * KHALF;
  int lb = wg * 512;            // wave-uniform LDS chunk base (elems): +jj*1024

#define STAGE(pbuf, t_) do {                                                   \
    size_t ko_ = (size_t)(t_) * 32;                                            \
    _Pragma("unroll")                                                          \
    for (int jj = 0; jj < 4; ++jj)                                             \
      gload_lds16(pA + (size_t)jj * 32 * strA + ko_, (pbuf) + jj * 1024 + lb); \
    _Pragma("unroll")                                                          \
    for (int jj = 0; jj < 2; ++jj)                                             \
      gload_lds16(pB + (size_t)jj * 32 * Ktot + ko_, (pbuf) + 4096 + jj * 1024 + lb); \
  } while (0)

  f32x4 acc[4][4] = {};

#define COMPUTE(pbuf) do {                                                     \
    bf16x8 af[4], bv[4];                                                       \
    _Pragma("unroll")                                                          \
    for (int m = 0; m < 4; ++m)                                                \
      af[m] = *(const bf16x8*)((pbuf) + (wrow + m * 16 + fr) * 32 + ch);       \
    _Pragma("unroll")                                                          \
    for (int n = 0; n < 4; ++n)                                                \
      bv[n] = *(const bf16x8*)((pbuf) + 4096 + (n * 16 + fr) * 32 + ch);       \
    __builtin_amdgcn_s_setprio(1);                                             \
    _Pragma("unroll")                                                          \
    for (int m = 0; m < 4; ++m)                                                \
      _Pragma("unroll")                                                        \
      for (int n = 0; n < 4; ++n)                                              \
        acc[m][n] = __builtin_amdgcn_mfma_f32_16x16x32_bf16(af[m], bv[n], acc[m][n], 0, 0, 0); \
    __builtin_amdgcn_s_setprio(0);                                             \
  } while (0)

  bf16* p0 = &lds[g][0][0];
  bf16* p1 = &lds[g][1][0];
  bf16* p2 = &lds[g][2][0];

  STAGE(p0, 0);
  STAGE(p1, 1);
  #pragma unroll 1
  for (int t = 0; t < NSTEP; ++t) {
    if (t < NSTEP - 1) asm volatile("s_waitcnt vmcnt(6)" ::: "memory");
    else               asm volatile("s_waitcnt vmcnt(0)" ::: "memory");
    __builtin_amdgcn_s_barrier();        // stage(t) published; t-1 reads retired
    asm volatile("" ::: "memory");
    if (t + 2 < NSTEP) STAGE(p2, t + 2); // overwrites buffer last read at t-1
    COMPUTE(p0);
    bf16* tmp = p0; p0 = p1; p1 = p2; p2 = tmp;
  }
#undef COMPUTE
#undef STAGE

  // ---- cross-group reduction via LDS (reuse tile space), fused epilogue ----
  __syncthreads();
  float* xch = (float*)&lds[0][0][0];    // 2 waves x 16 KB = 32 KB
  if (g == 1) {
    #pragma unroll
    for (int m = 0; m < 4; ++m)
      #pragma unroll
      for (int n = 0; n < 4; ++n)
        *(f32x4*)&xch[wg * 4096 + (m * 4 + n) * 256 + lane * 4] = acc[m][n];
  }
  __syncthreads();
  if (g == 0) {
    // C/D layout: col = lane&15, row = (lane>>4)*4 + i  [m89 verified]
    int row0 = tm * 128 + wrow + fq * 4;
    int col0 = tn * 64 + fr;
    #pragma unroll
    for (int n = 0; n < 4; ++n) {
      int gcol = col0 + n * 16;
      float bv2 = bias[gcol];
      #pragma unroll
      for (int m = 0; m < 4; ++m) {
        f32x4 part = *(const f32x4*)&xch[wg * 4096 + (m * 4 + n) * 256 + lane * 4];
        #pragma unroll
        for (int i = 0; i < 4; ++i) {
          int grow = row0 + m * 16 + i;
          size_t idx = (size_t)grow * Hdim + gcol;
          float v = acc[m][n][i] + part[i] + bv2;
          if (EPI == 0) {
            float fg = (v + 1.0f) * 0.5f;
            OMF[idx] = (bf16)(1.0f - fg);
            A2L[idx] = (bf16)(fg * hx[idx]);
          } else {
            OUT[idx] = (float)OMF[idx] * v + (float)A2L[idx];  // (1-fg)*ng + fg*hx
          }
        }
      }
    }
  }
}

extern "C" void kernel_launch(void* const* d_in, const int* in_sizes, int n_in,
                              void* d_out, int out_size, void* d_ws, size_t ws_size,
                              hipStream_t stream) {
  const float* x   = (const float*)d_in[0];
  const float* hx  = (const float*)d_in[1];
  const float* w_f = (const float*)d_in[2];
  const float* b_f = (const float*)d_in[3];
  const float* w_n = (const float*)d_in[4];
  const float* b_n = (const float*)d_in[5];
  float* out = (float*)d_out;

  bf16* A1  = (bf16*)d_ws;                         // [2048][4096] = 16 MB
  bf16* A2L = A1  + (size_t)Bdim * Ktot;           // [2048][2048] =  8 MB
  bf16* Wf  = A2L + (size_t)Bdim * KHALF;          // [2048][4096] = 16 MB
  bf16* Wn  = Wf  + (size_t)Hdim * Ktot;           // [2048][4096] = 16 MB
  bf16* OMF = Wn  + (size_t)Hdim * Ktot;           // [2048][2048] =  8 MB
  // ws total: 64 MB

  prep_kernel<<<2048, 256, 0, stream>>>(w_f, w_n, hx, x, Wf, Wn, A1);

  // GEMM1: A = A1 (group 0: K 0..2047, group 1: K 2048..4095); -> OMF + A2L.
  gemm_kernel<0><<<512, 256, 0, stream>>>(A1, Ktot, A1, Ktot, Wf, b_f,
                                          hx, OMF, A2L, nullptr);
  // GEMM2: group 0 A = A2L (fg*hx, stride 2048); group 1 A = A1+Hdim (x).
  gemm_kernel<1><<<512, 256, 0, stream>>>(A2L, KHALF, A1 + Hdim, Ktot, Wn, b_n,
                                          nullptr, OMF, A2L, out);
}

// Round 17
// 112.943 us; speedup vs baseline: 1.3194x; 1.3194x over previous
//
#include <hip/hip_runtime.h>
#include <stdint.h>

// FSUMGUCell: hy = (1-fg)*ng + fg*hx
//   fg = ( [hx|x]@w_f^T + b_f + 1 ) * 0.5
//   ng =   [fg*hx|x]@w_n^T + b_n
// B=H=I=2048, K=H+I=4096. bf16 MFMA path.
//
// Round 17 = REVERT to round-11 (verified best, 112.9 us). Session findings:
//  - 1 block/CU -> bubbles (r1/r3); shared barrier -> in-block split-K groups
//    can't decouple (r4/r6/r14 null); cross-block combine -> +20us plumbing
//    (r9) or cross-XCD fence collapse (r13); >2 blocks/CU -> L2 ceiling.
//  - r16's BK=32 added 4.19M bank conflicts + 52MB over-fetch; reverted.
//  - fp8 excluded by error budget (projected absmax > threshold).
// This config: 128x64 tiles, full K, 4 waves (64x32 each), BK=64 dbuf 48KB,
// 2 blocks/CU, counted vmcnt(6), XOR swizzle (0 conflicts), fused epilogues.

#define Hdim 2048
#define Idim 2048
#define Bdim 2048
#define Ktot 4096
#define KHALF 2048
#define NSTEP 64            // Ktot / 64
#define NSTEP2 32           // K-half boundary in BK units

typedef __bf16 bf16;
typedef __bf16 bf16x8 __attribute__((ext_vector_type(8)));
typedef float  f32x4  __attribute__((ext_vector_type(4)));

__device__ __forceinline__ void gload_lds16(const bf16* g, bf16* l) {
  __builtin_amdgcn_global_load_lds(
      (const __attribute__((address_space(1))) unsigned int*)g,
      (__attribute__((address_space(3))) unsigned int*)l,
      16, 0, 0);
}

__device__ __forceinline__ void cvt8(const float* __restrict__ src, bf16* __restrict__ dst) {
  const float4* s = (const float4*)src;
  float4 a = s[0], b = s[1];
  bf16x8 o;
  o[0]=(bf16)a.x; o[1]=(bf16)a.y; o[2]=(bf16)a.z; o[3]=(bf16)a.w;
  o[4]=(bf16)b.x; o[5]=(bf16)b.y; o[6]=(bf16)b.z; o[7]=(bf16)b.w;
  *(bf16x8*)dst = o;
}

// ---- fused prep: Wf cvt | Wn cvt | A1 = [hx|x] cvt (all f32 -> bf16 x8) ----
__global__ void prep_kernel(const float* __restrict__ w_f, const float* __restrict__ w_n,
                            const float* __restrict__ hx, const float* __restrict__ x,
                            bf16* __restrict__ Wf, bf16* __restrict__ Wn,
                            bf16* __restrict__ A1) {
  const int n8 = Hdim * Ktot / 8;
  int stride = gridDim.x * blockDim.x;
  for (int i = blockIdx.x * blockDim.x + threadIdx.x; i < 3 * n8; i += stride) {
    if (i < n8) {
      cvt8(w_f + (size_t)i * 8, Wf + (size_t)i * 8);
    } else if (i < 2 * n8) {
      int j = i - n8;
      cvt8(w_n + (size_t)j * 8, Wn + (size_t)j * 8);
    } else {
      int j = i - 2 * n8;
      int e = j * 8;
      int b = e >> 12;            // / 4096
      int k = e & (Ktot - 1);
      const float* src = (k < Hdim) ? (hx + (size_t)b * Hdim + k)
                                    : (x  + (size_t)b * Idim + (k - Hdim));
      cvt8(src, A1 + (size_t)e);
    }
  }
}

// ---- 128x64 x K=4096 GEMM, 4 waves, dbuf + counted vmcnt, fused epilogue ----
// grid 512 = 16 tm x 32 tn. C[row][col] = sum_k A[row][k] * W[col][k].
// A K-halves: (Ab0,sA0) for k<2048, (Ab1,sA1) for k>=2048 (GEMM1: both = A1;
// GEMM2: A2L then A1+Hdim). LDS [buf][A 128x64 | B 64x64] bf16 = 48 KB;
// 16B-chunk XOR swizzle: LDS[row][c] holds global chunk c ^ (row&7), staged
// via inverse-swizzled global source (global_load_lds writes linearly);
// read applies the same XOR.
template<int EPI>
__global__ __launch_bounds__(256, 2)
void gemm_kernel(const bf16* __restrict__ Ab0, int sA0,
                 const bf16* __restrict__ Ab1, int sA1,
                 const bf16* __restrict__ W,
                 const float* __restrict__ bias,
                 const float* __restrict__ hx,   // EPI0 only
                 bf16* __restrict__ OMF,         // EPI0: write (1-fg) ; EPI1: read
                 bf16* __restrict__ A2L,         // EPI0: write bf16(fg*hx) ; EPI1: read
                 float* __restrict__ OUT)        // EPI1: write hy
{
  __shared__ bf16 lds[2][12288];   // [buf][ A:0..8191 | B:8192..12287 ] = 48 KB

  int bid  = blockIdx.x;
  int sbid = (bid & 7) * 64 + (bid >> 3);   // XCD swizzle (512%8==0, bijective)
  int tm = sbid >> 5, tn = sbid & 31;       // 16 x 32 tiles of 128x64

  int tid = threadIdx.x;
  int w = tid >> 6, lane = tid & 63;
  int wrow = (w >> 1) * 64;     // 2x2 wave grid over 128x64: 64x32 per wave
  int wcol = (w & 1) * 32;
  int fr = lane & 15, fq = lane >> 4;
  int swz = fr & 7;

  // staging: A 1024 + B 512 16B chunks/step, 256 thr -> 6 loads/thread.
  // Thread t: row = jj*32 + (t>>3), dest chunk t&7, src chunk (t&7)^(row&7).
  int srow = tid >> 3;                  // 0..31
  int csrc = (tid & 7) ^ (srow & 7);

  const bf16* pA0 = Ab0 + (size_t)(tm * 128 + srow) * sA0 + csrc * 8;
  const bf16* pA1 = Ab1 + (size_t)(tm * 128 + srow) * sA1 + csrc * 8;
  const bf16* pB  = W   + (size_t)(tn * 64  + srow) * Ktot + csrc * 8;
  int lb = w * 512;                     // wave-uniform LDS base; gload adds lane*16B

#define STAGE(buf, t_) do {                                                    \
    const bf16* pa_ = ((t_) < NSTEP2) ? pA0 : pA1;                             \
    size_t sa_ = ((t_) < NSTEP2) ? (size_t)sA0 : (size_t)sA1;                  \
    size_t ko_ = ((t_) < NSTEP2) ? (size_t)(t_) * 64 : (size_t)((t_) - NSTEP2) * 64; \
    _Pragma("unroll")                                                          \
    for (int jj = 0; jj < 4; ++jj)                                             \
      gload_lds16(pa_ + (size_t)jj * 32 * sa_ + ko_, &lds[buf][jj * 2048 + lb]); \
    _Pragma("unroll")                                                          \
    for (int jj = 0; jj < 2; ++jj)                                             \
      gload_lds16(pB + (size_t)jj * 32 * Ktot + (size_t)(t_) * 64,             \
                  &lds[buf][8192 + jj * 2048 + lb]);                           \
  } while (0)

  f32x4 acc[4][2] = {};

  auto compute = [&](int buf) {
    #pragma unroll
    for (int kk = 0; kk < 2; ++kk) {
      bf16x8 af[4], bv[2];
      int ch = ((kk * 4 + fq) ^ swz) * 8;
      #pragma unroll
      for (int m = 0; m < 4; ++m)
        af[m] = *(const bf16x8*)&lds[buf][(wrow + m * 16 + fr) * 64 + ch];
      #pragma unroll
      for (int n = 0; n < 2; ++n)
        bv[n] = *(const bf16x8*)&lds[buf][8192 + (wcol + n * 16 + fr) * 64 + ch];
      __builtin_amdgcn_s_setprio(1);
      #pragma unroll
      for (int m = 0; m < 4; ++m)
        #pragma unroll
        for (int n = 0; n < 2; ++n)
          acc[m][n] = __builtin_amdgcn_mfma_f32_16x16x32_bf16(af[m], bv[n], acc[m][n], 0, 0, 0);
      __builtin_amdgcn_s_setprio(0);
    }
  };

  STAGE(0, 0);
  int cur = 0;
  for (int t = 0; t < NSTEP - 1; ++t) {
    STAGE(cur ^ 1, t + 1);                             // prefetch next K-tile
    asm volatile("s_waitcnt vmcnt(6)" ::: "memory");   // cur's 6 done; next 6 fly
    __builtin_amdgcn_s_barrier();
    compute(cur);
    __builtin_amdgcn_s_barrier();                      // reads done -> buf reusable
    cur ^= 1;
  }
  asm volatile("s_waitcnt vmcnt(0)" ::: "memory");
  __builtin_amdgcn_s_barrier();
  compute(cur);
#undef STAGE

  // ---- fused epilogue. C/D layout: col = lane&15, row = (lane>>4)*4+i [m89]
  int row0 = tm * 128 + wrow + fq * 4;
  int col0 = tn * 64 + wcol + fr;
  #pragma unroll
  for (int n = 0; n < 2; ++n) {
    int gcol = col0 + n * 16;
    float bv2 = bias[gcol];
    #pragma unroll
    for (int m = 0; m < 4; ++m) {
      #pragma unroll
      for (int i = 0; i < 4; ++i) {
        int grow = row0 + m * 16 + i;
        size_t idx = (size_t)grow * Hdim + gcol;
        float v = acc[m][n][i] + bv2;
        if (EPI == 0) {
          float fg = (v + 1.0f) * 0.5f;
          OMF[idx] = (bf16)(1.0f - fg);
          A2L[idx] = (bf16)(fg * hx[idx]);
        } else {
          OUT[idx] = (float)OMF[idx] * v + (float)A2L[idx];  // (1-fg)*ng + fg*hx
        }
      }
    }
  }
}

extern "C" void kernel_launch(void* const* d_in, const int* in_sizes, int n_in,
                              void* d_out, int out_size, void* d_ws, size_t ws_size,
                              hipStream_t stream) {
  const float* x   = (const float*)d_in[0];
  const float* hx  = (const float*)d_in[1];
  const float* w_f = (const float*)d_in[2];
  const float* b_f = (const float*)d_in[3];
  const float* w_n = (const float*)d_in[4];
  const float* b_n = (const float*)d_in[5];
  float* out = (float*)d_out;

  bf16* A1  = (bf16*)d_ws;                         // [2048][4096] = 16 MB
  bf16* A2L = A1  + (size_t)Bdim * Ktot;           // [2048][2048] =  8 MB
  bf16* Wf  = A2L + (size_t)Bdim * KHALF;          // [2048][4096] = 16 MB
  bf16* Wn  = Wf  + (size_t)Hdim * Ktot;           // [2048][4096] = 16 MB
  bf16* OMF = Wn  + (size_t)Hdim * Ktot;           // [2048][2048] =  8 MB
  // ws total: 64 MB

  prep_kernel<<<2048, 256, 0, stream>>>(w_f, w_n, hx, x, Wf, Wn, A1);

  // GEMM1: A = A1 (both K-halves); fused epilogue -> OMF + A2L.
  gemm_kernel<0><<<512, 256, 0, stream>>>(A1, Ktot, A1 + KHALF, Ktot, Wf, b_f,
                                          hx, OMF, A2L, nullptr);
  // GEMM2: A = [A2L | A1 right half (x)]; fused epilogue -> hy.
  gemm_kernel<1><<<512, 256, 0, stream>>>(A2L, KHALF, A1 + Hdim, Ktot, Wn, b_n,
                                          nullptr, OMF, A2L, out);
}

// Round 18
// 112.733 us; speedup vs baseline: 1.3219x; 1.0019x over previous
//
#include <hip/hip_runtime.h>
#include <stdint.h>

// FSUMGUCell: hy = (1-fg)*ng + fg*hx
//   fg = ( [hx|x]@w_f^T + b_f + 1 ) * 0.5
//   ng =   [fg*hx|x]@w_n^T + b_n
// B=H=I=2048, K=H+I=4096. bf16 MFMA path.
//
// Round 18 = r17 (verified 112.9us) + Wn-convert folded into GEMM1's tail.
// Wn is consumed only by GEMM2; each GEMM1 block converts slice blockIdx
// (deterministic, no tickets/fences — the GEMM1->GEMM2 dispatch boundary on
// one stream guarantees visibility). Moves 48 MB of HBM traffic from the
// serial prep phase (HBM-bound) under GEMM1 (27% HBM, has headroom).
// Prep shrinks to Wf + A1 (96 -> 64 MB).
// GEMM core byte-identical to r17: 128x64 tiles, full K, 4 waves (64x32),
// BK=64 dbuf 48KB, 2 blocks/CU, counted vmcnt(6), XOR swizzle, fused epi.

#define Hdim 2048
#define Idim 2048
#define Bdim 2048
#define Ktot 4096
#define KHALF 2048
#define NSTEP 64            // Ktot / 64
#define NSTEP2 32           // K-half boundary in BK units

typedef __bf16 bf16;
typedef __bf16 bf16x8 __attribute__((ext_vector_type(8)));
typedef float  f32x4  __attribute__((ext_vector_type(4)));

__device__ __forceinline__ void gload_lds16(const bf16* g, bf16* l) {
  __builtin_amdgcn_global_load_lds(
      (const __attribute__((address_space(1))) unsigned int*)g,
      (__attribute__((address_space(3))) unsigned int*)l,
      16, 0, 0);
}

__device__ __forceinline__ void cvt8(const float* __restrict__ src, bf16* __restrict__ dst) {
  const float4* s = (const float4*)src;
  float4 a = s[0], b = s[1];
  bf16x8 o;
  o[0]=(bf16)a.x; o[1]=(bf16)a.y; o[2]=(bf16)a.z; o[3]=(bf16)a.w;
  o[4]=(bf16)b.x; o[5]=(bf16)b.y; o[6]=(bf16)b.z; o[7]=(bf16)b.w;
  *(bf16x8*)dst = o;
}

// ---- prep: Wf cvt | A1 = [hx|x] cvt (Wn converted by GEMM1 blocks) ----
__global__ void prep_kernel(const float* __restrict__ w_f,
                            const float* __restrict__ hx, const float* __restrict__ x,
                            bf16* __restrict__ Wf, bf16* __restrict__ A1) {
  const int n8 = Hdim * Ktot / 8;
  int stride = gridDim.x * blockDim.x;
  for (int i = blockIdx.x * blockDim.x + threadIdx.x; i < 2 * n8; i += stride) {
    if (i < n8) {
      cvt8(w_f + (size_t)i * 8, Wf + (size_t)i * 8);
    } else {
      int j = i - n8;
      int e = j * 8;
      int b = e >> 12;            // / 4096
      int k = e & (Ktot - 1);
      const float* src = (k < Hdim) ? (hx + (size_t)b * Hdim + k)
                                    : (x  + (size_t)b * Idim + (k - Hdim));
      cvt8(src, A1 + (size_t)e);
    }
  }
}

// ---- 128x64 x K=4096 GEMM, 4 waves, dbuf + counted vmcnt, fused epilogue ----
// grid 512 = 16 tm x 32 tn. C[row][col] = sum_k A[row][k] * W[col][k].
// A K-halves: (Ab0,sA0) for k<2048, (Ab1,sA1) for k>=2048 (GEMM1: both = A1;
// GEMM2: A2L then A1+Hdim). LDS [buf][A 128x64 | B 64x64] bf16 = 48 KB;
// 16B-chunk XOR swizzle: LDS[row][c] holds global chunk c ^ (row&7), staged
// via inverse-swizzled global source (global_load_lds writes linearly);
// read applies the same XOR.
template<int EPI>
__global__ __launch_bounds__(256, 2)
void gemm_kernel(const bf16* __restrict__ Ab0, int sA0,
                 const bf16* __restrict__ Ab1, int sA1,
                 const bf16* __restrict__ W,
                 const float* __restrict__ bias,
                 const float* __restrict__ hx,      // EPI0 only
                 const float* __restrict__ wn_src,  // EPI0: Wn f32 slice convert
                 bf16* __restrict__ wn_dst,         // EPI0
                 bf16* __restrict__ OMF,            // EPI0: write (1-fg) ; EPI1: read
                 bf16* __restrict__ A2L,            // EPI0: write bf16(fg*hx) ; EPI1: read
                 float* __restrict__ OUT)           // EPI1: write hy
{
  __shared__ bf16 lds[2][12288];   // [buf][ A:0..8191 | B:8192..12287 ] = 48 KB

  int bid  = blockIdx.x;
  int sbid = (bid & 7) * 64 + (bid >> 3);   // XCD swizzle (512%8==0, bijective)
  int tm = sbid >> 5, tn = sbid & 31;       // 16 x 32 tiles of 128x64

  int tid = threadIdx.x;
  int w = tid >> 6, lane = tid & 63;
  int wrow = (w >> 1) * 64;     // 2x2 wave grid over 128x64: 64x32 per wave
  int wcol = (w & 1) * 32;
  int fr = lane & 15, fq = lane >> 4;
  int swz = fr & 7;

  // staging: A 1024 + B 512 16B chunks/step, 256 thr -> 6 loads/thread.
  // Thread t: row = jj*32 + (t>>3), dest chunk t&7, src chunk (t&7)^(row&7).
  int srow = tid >> 3;                  // 0..31
  int csrc = (tid & 7) ^ (srow & 7);

  const bf16* pA0 = Ab0 + (size_t)(tm * 128 + srow) * sA0 + csrc * 8;
  const bf16* pA1 = Ab1 + (size_t)(tm * 128 + srow) * sA1 + csrc * 8;
  const bf16* pB  = W   + (size_t)(tn * 64  + srow) * Ktot + csrc * 8;
  int lb = w * 512;                     // wave-uniform LDS base; gload adds lane*16B

#define STAGE(buf, t_) do {                                                    \
    const bf16* pa_ = ((t_) < NSTEP2) ? pA0 : pA1;                             \
    size_t sa_ = ((t_) < NSTEP2) ? (size_t)sA0 : (size_t)sA1;                  \
    size_t ko_ = ((t_) < NSTEP2) ? (size_t)(t_) * 64 : (size_t)((t_) - NSTEP2) * 64; \
    _Pragma("unroll")                                                          \
    for (int jj = 0; jj < 4; ++jj)                                             \
      gload_lds16(pa_ + (size_t)jj * 32 * sa_ + ko_, &lds[buf][jj * 2048 + lb]); \
    _Pragma("unroll")                                                          \
    for (int jj = 0; jj < 2; ++jj)                                             \
      gload_lds16(pB + (size_t)jj * 32 * Ktot + (size_t)(t_) * 64,             \
                  &lds[buf][8192 + jj * 2048 + lb]);                           \
  } while (0)

  f32x4 acc[4][2] = {};

  auto compute = [&](int buf) {
    #pragma unroll
    for (int kk = 0; kk < 2; ++kk) {
      bf16x8 af[4], bv[2];
      int ch = ((kk * 4 + fq) ^ swz) * 8;
      #pragma unroll
      for (int m = 0; m < 4; ++m)
        af[m] = *(const bf16x8*)&lds[buf][(wrow + m * 16 + fr) * 64 + ch];
      #pragma unroll
      for (int n = 0; n < 2; ++n)
        bv[n] = *(const bf16x8*)&lds[buf][8192 + (wcol + n * 16 + fr) * 64 + ch];
      __builtin_amdgcn_s_setprio(1);
      #pragma unroll
      for (int m = 0; m < 4; ++m)
        #pragma unroll
        for (int n = 0; n < 2; ++n)
          acc[m][n] = __builtin_amdgcn_mfma_f32_16x16x32_bf16(af[m], bv[n], acc[m][n], 0, 0, 0);
      __builtin_amdgcn_s_setprio(0);
    }
  };

  STAGE(0, 0);
  int cur = 0;
  for (int t = 0; t < NSTEP - 1; ++t) {
    STAGE(cur ^ 1, t + 1);                             // prefetch next K-tile
    asm volatile("s_waitcnt vmcnt(6)" ::: "memory");   // cur's 6 done; next 6 fly
    __builtin_amdgcn_s_barrier();
    compute(cur);
    __builtin_amdgcn_s_barrier();                      // reads done -> buf reusable
    cur ^= 1;
  }
  asm volatile("s_waitcnt vmcnt(0)" ::: "memory");
  __builtin_amdgcn_s_barrier();
  compute(cur);
#undef STAGE

  // ---- fused epilogue. C/D layout: col = lane&15, row = (lane>>4)*4+i [m89]
  int row0 = tm * 128 + wrow + fq * 4;
  int col0 = tn * 64 + wcol + fr;
  #pragma unroll
  for (int n = 0; n < 2; ++n) {
    int gcol = col0 + n * 16;
    float bv2 = bias[gcol];
    #pragma unroll
    for (int m = 0; m < 4; ++m) {
      #pragma unroll
      for (int i = 0; i < 4; ++i) {
        int grow = row0 + m * 16 + i;
        size_t idx = (size_t)grow * Hdim + gcol;
        float v = acc[m][n][i] + bv2;
        if (EPI == 0) {
          float fg = (v + 1.0f) * 0.5f;
          OMF[idx] = (bf16)(1.0f - fg);
          A2L[idx] = (bf16)(fg * hx[idx]);
        } else {
          OUT[idx] = (float)OMF[idx] * v + (float)A2L[idx];  // (1-fg)*ng + fg*hx
        }
      }
    }
  }

  // ---- EPI0 tail: convert this block's deterministic 1/512 slice of Wn ----
  // Visibility to GEMM2 via the dispatch boundary (same stream) — no fences.
  if (EPI == 0) {
    const int CH = (Hdim * Ktot / 8) / 512;   // 2048 chunks per slice
    size_t base = (size_t)bid * CH;
    for (int c = tid; c < CH; c += 256)
      cvt8(wn_src + (base + c) * 8, wn_dst + (base + c) * 8);
  }
}

extern "C" void kernel_launch(void* const* d_in, const int* in_sizes, int n_in,
                              void* d_out, int out_size, void* d_ws, size_t ws_size,
                              hipStream_t stream) {
  const float* x   = (const float*)d_in[0];
  const float* hx  = (const float*)d_in[1];
  const float* w_f = (const float*)d_in[2];
  const float* b_f = (const float*)d_in[3];
  const float* w_n = (const float*)d_in[4];
  const float* b_n = (const float*)d_in[5];
  float* out = (float*)d_out;

  bf16* A1  = (bf16*)d_ws;                         // [2048][4096] = 16 MB
  bf16* A2L = A1  + (size_t)Bdim * Ktot;           // [2048][2048] =  8 MB
  bf16* Wf  = A2L + (size_t)Bdim * KHALF;          // [2048][4096] = 16 MB
  bf16* Wn  = Wf  + (size_t)Hdim * Ktot;           // [2048][4096] = 16 MB
  bf16* OMF = Wn  + (size_t)Hdim * Ktot;           // [2048][2048] =  8 MB
  // ws total: 64 MB

  prep_kernel<<<2048, 256, 0, stream>>>(w_f, hx, x, Wf, A1);

  // GEMM1: A = A1 (both K-halves); fused epilogue -> OMF + A2L; tail cvt Wn.
  gemm_kernel<0><<<512, 256, 0, stream>>>(A1, Ktot, A1 + KHALF, Ktot, Wf, b_f,
                                          hx, w_n, Wn, OMF, A2L, nullptr);
  // GEMM2: A = [A2L | A1 right half (x)]; fused epilogue -> hy.
  gemm_kernel<1><<<512, 256, 0, stream>>>(A2L, KHALF, A1 + Hdim, Ktot, Wn, b_n,
                                          nullptr, nullptr, nullptr, OMF, A2L, out);
}